// Round 6
// baseline (206.658 us; speedup 1.0000x reference)
//
#include <hip/hip_runtime.h>

// B=256, T=5, S=64, F=256, H=4, Fh=64, N=H*B=1024, M=81920 rows of [.,256]

typedef unsigned short ushort_t;
typedef __attribute__((ext_vector_type(8))) short bf16x8;
typedef __attribute__((ext_vector_type(4))) float f32x4;

__device__ inline ushort_t f2bf(float f) {            // RNE f32 -> bf16
  unsigned u = __float_as_uint(f);
  return (ushort_t)((u + 0x7FFFu + ((u >> 16) & 1u)) >> 16);
}
__device__ inline float bflo(unsigned u) { return __uint_as_float(u << 16); }
__device__ inline float bfhi(unsigned u) { return __uint_as_float(u & 0xFFFF0000u); }

// ---------------- prior[t,s,c] ----------------------------------------------------
__global__ __launch_bounds__(256) void prior_kernel(const float* __restrict__ dis,
                                                    const float* __restrict__ sigma,
                                                    float* __restrict__ prior) {
  int i = blockIdx.x * 256 + threadIdx.x;
  if (i >= 5 * 64 * 64) return;
  int ts = i >> 6;
  float sg = sigma[ts];
  float d = dis[i];
  prior[i] = 0.3989422804014327f / sg * __expf(-d * d / (2.f * sg * sg));
}

// ---------------- bps[nb,t,c] = sum_s bias[nb,t,s,c]*prior[t,s,c] -----------------
__global__ __launch_bounds__(256) void bias_prior_sum(const float* __restrict__ bias,
                                                      const float* __restrict__ prior,
                                                      float* __restrict__ bps) {
  int blk = blockIdx.x;              // nb*5 + t, 1280 blocks
  int t = blk % 5, tid = threadIdx.x;
  const float* bp = bias + (size_t)blk * 4096;
  const float* pp = prior + t * 4096;
  int c = tid & 63, sg = tid >> 6;
  float sum = 0.f;
  for (int s = sg * 16; s < sg * 16 + 16; ++s)
    sum += bp[s * 64 + c] * pp[s * 64 + c];
  __shared__ float red[4][64];
  red[sg][c] = sum;
  __syncthreads();
  if (tid < 64)
    bps[(size_t)blk * 64 + tid] = red[0][tid] + red[1][tid] + red[2][tid] + red[3][tid];
}

// ---------------- k[b,s,f] = sum_t u[t]*x -> bf16;  xb = bf16(x) ------------------
__global__ __launch_bounds__(256) void k_kernel(const float* __restrict__ x,
                                                const float* __restrict__ u,
                                                ushort_t* __restrict__ kout,
                                                ushort_t* __restrict__ xb) {
  int i = blockIdx.x * 256 + threadIdx.x;      // float4 id, total 1048576
  size_t j = (size_t)i * 4;
  int b = (int)(j >> 14);
  int off = (int)(j & 16383);
  const float* xp = x + (size_t)b * 81920 + off;
  ushort_t* xq = xb + (size_t)b * 81920 + off;
  float u0 = u[0], u1 = u[1], u2 = u[2], u3 = u[3], u4 = u[4];
  float4 a0 = *(const float4*)(xp);
  float4 a1 = *(const float4*)(xp + 16384);
  float4 a2 = *(const float4*)(xp + 32768);
  float4 a3 = *(const float4*)(xp + 49152);
  float4 a4 = *(const float4*)(xp + 65536);
  ushort4 h0 = {f2bf(a0.x), f2bf(a0.y), f2bf(a0.z), f2bf(a0.w)};
  ushort4 h1 = {f2bf(a1.x), f2bf(a1.y), f2bf(a1.z), f2bf(a1.w)};
  ushort4 h2 = {f2bf(a2.x), f2bf(a2.y), f2bf(a2.z), f2bf(a2.w)};
  ushort4 h3 = {f2bf(a3.x), f2bf(a3.y), f2bf(a3.z), f2bf(a3.w)};
  ushort4 h4 = {f2bf(a4.x), f2bf(a4.y), f2bf(a4.z), f2bf(a4.w)};
  *(ushort4*)(xq) = h0;
  *(ushort4*)(xq + 16384) = h1;
  *(ushort4*)(xq + 32768) = h2;
  *(ushort4*)(xq + 49152) = h3;
  *(ushort4*)(xq + 65536) = h4;
  float4 r;
  r.x = u0 * a0.x + u1 * a1.x + u2 * a2.x + u3 * a3.x + u4 * a4.x;
  r.y = u0 * a0.y + u1 * a1.y + u2 * a2.y + u3 * a3.y + u4 * a4.y;
  r.z = u0 * a0.z + u1 * a1.z + u2 * a2.z + u3 * a3.z + u4 * a4.z;
  r.w = u0 * a0.w + u1 * a1.w + u2 * a2.w + u3 * a3.w + u4 * a4.w;
  ushort4 h = {f2bf(r.x), f2bf(r.y), f2bf(r.z), f2bf(r.w)};
  *(ushort4*)(kout + j) = h;
}

// ---------------- W^T convert: Wt[mat][n][k] = bf16(W[k][n]) ----------------------
__global__ __launch_bounds__(256) void convert_w(const float* __restrict__ Wq,
                                                 const float* __restrict__ Wv,
                                                 const float* __restrict__ Wo,
                                                 ushort_t* __restrict__ Wt) {
  int id = blockIdx.x * 256 + threadIdx.x;     // 196608
  if (id >= 196608) return;
  int mat = id >> 16, rem = id & 65535;
  int n = rem >> 8, k = rem & 255;
  const float* W = mat == 0 ? Wq : (mat == 1 ? Wv : Wo);
  Wt[id] = f2bf(W[k * 256 + n]);
}

// ---------------- fused q-GEMM + score --------------------------------------------
// One block per n (1024). GEMM: q80x256 = xb[n*80..+80] @ Wq^T, output to LDS as
// [t][s][fh] (t=mi, s=16ql+4rr+w, fh=ni*16+cl). Then score per t:
// ssum[n,t,c] = sum_s sigmoid(qk/8)*prior[t,s,c] - bps[n%256,t,c].
__global__ __launch_bounds__(256) void qscore(const ushort_t* __restrict__ xb,
                                              const ushort_t* __restrict__ Wtq,
                                              const ushort_t* __restrict__ kbuf,
                                              const float* __restrict__ prior,
                                              const float* __restrict__ bps,
                                              float* __restrict__ ssum) {
  __shared__ __align__(16) ushort_t qlds[5 * 64 * 72];   // 46 KB, stride 72 (16B-aligned)
  const int n = blockIdx.x;
  const int tid = threadIdx.x;
  const int lane = tid & 63, w = tid >> 6;
  const int cl = lane & 15, ql = lane >> 4;
  const ushort_t* A = xb + (size_t)n * 20480;            // 80 rows x 256

  f32x4 acc[5][4];
#pragma unroll
  for (int mi = 0; mi < 5; ++mi)
#pragma unroll
    for (int ni = 0; ni < 4; ++ni) acc[mi][ni] = (f32x4){0.f, 0.f, 0.f, 0.f};

#pragma unroll
  for (int kk = 0; kk < 8; ++kk) {
    bf16x8 bfr[4];
#pragma unroll
    for (int ni = 0; ni < 4; ++ni)
      bfr[ni] = *(const bf16x8*)(Wtq + (size_t)(w * 64 + ni * 16 + cl) * 256 + kk * 32 + ql * 8);
#pragma unroll
    for (int mi = 0; mi < 5; ++mi) {
      bf16x8 afr = *(const bf16x8*)(A + (size_t)(mi * 16 + cl) * 256 + kk * 32 + ql * 8);
#pragma unroll
      for (int ni = 0; ni < 4; ++ni)
        acc[mi][ni] = __builtin_amdgcn_mfma_f32_16x16x32_bf16(afr, bfr[ni], acc[mi][ni], 0, 0, 0);
    }
  }
  // epilogue -> LDS [t=mi][s=16ql+4rr+w][fh=ni*16+cl]
#pragma unroll
  for (int mi = 0; mi < 5; ++mi)
#pragma unroll
    for (int ni = 0; ni < 4; ++ni)
#pragma unroll
      for (int rr = 0; rr < 4; ++rr)
        qlds[(mi * 64 + 16 * ql + 4 * rr + w) * 72 + ni * 16 + cl] = f2bf(acc[mi][ni][rr]);
  __syncthreads();

  // score phase: wave w owns cols c = w*16 + cl
  const int c = w * 16 + cl;
  const int nb = n & 255;
  const ushort_t* kbp = kbuf + (size_t)(n >> 2) * 16384 + (n & 3) * 64;
  bf16x8 kfr0 = *(const bf16x8*)(kbp + c * 256 + ql * 8);
  bf16x8 kfr1 = *(const bf16x8*)(kbp + c * 256 + ql * 8 + 32);
#pragma unroll
  for (int t = 0; t < 5; ++t) {
    f32x4 sacc[4];
#pragma unroll
    for (int si = 0; si < 4; ++si) {
      bf16x8 a0 = *(const bf16x8*)&qlds[(t * 64 + si * 16 + cl) * 72 + ql * 8];
      bf16x8 a1 = *(const bf16x8*)&qlds[(t * 64 + si * 16 + cl) * 72 + ql * 8 + 32];
      f32x4 z = (f32x4){0.f, 0.f, 0.f, 0.f};
      z = __builtin_amdgcn_mfma_f32_16x16x32_bf16(a0, kfr0, z, 0, 0, 0);
      z = __builtin_amdgcn_mfma_f32_16x16x32_bf16(a1, kfr1, z, 0, 0, 0);
      sacc[si] = z;
    }
    const float* pp = prior + t * 4096;
    float colsum = 0.f;
#pragma unroll
    for (int si = 0; si < 4; ++si) {
#pragma unroll
      for (int r = 0; r < 4; ++r) {
        int s = si * 16 + ql * 4 + r;
        float sg = 1.f / (1.f + __expf(-sacc[si][r] * 0.125f));
        colsum += sg * pp[s * 64 + c];
      }
    }
    colsum += __shfl_xor(colsum, 16);
    colsum += __shfl_xor(colsum, 32);
    if (ql == 0)
      ssum[(size_t)n * 320 + t * 64 + c] = colsum - bps[((size_t)nb * 5 + t) * 64 + c];
  }
}

// ---------------- fused v-GEMM + o-GEMM -------------------------------------------
// BM=128, 512 thr = 8 waves (2x4). Phase 1: V = xb@Wv^T, scale by ssum, bf16 -> Vs
// (chunk-XOR swizzle: chunk' = chunk ^ (row&31)). Phase 2: O = Vs @ Wo^T -> ob,
// fused SE avg/max over the block's 2 complete (b,t) groups.
__global__ __launch_bounds__(512, 2) void vo_gemm(const ushort_t* __restrict__ xb,
                                                  const ushort_t* __restrict__ Wtv,
                                                  const ushort_t* __restrict__ Wto,
                                                  const float* __restrict__ ssum,
                                                  ushort_t* __restrict__ ob,
                                                  float* __restrict__ ravg,
                                                  float* __restrict__ rmax) {
  __shared__ __align__(16) ushort_t Vs[128 * 256];      // 64 KB
  __shared__ float redS[8], redM[8];
  const int tid = threadIdx.x;
  const int lane = tid & 63;
  const int w = tid >> 6, wr = w >> 2, wc = w & 3;
  const int cl = lane & 15, ql = lane >> 4;
  const int row0 = blockIdx.x * 128;

  f32x4 acc[4][4];
#pragma unroll
  for (int mi = 0; mi < 4; ++mi)
#pragma unroll
    for (int ni = 0; ni < 4; ++ni) acc[mi][ni] = (f32x4){0.f, 0.f, 0.f, 0.f};

#pragma unroll
  for (int kk = 0; kk < 8; ++kk) {
    bf16x8 bfr[4];
#pragma unroll
    for (int ni = 0; ni < 4; ++ni)
      bfr[ni] = *(const bf16x8*)(Wtv + (size_t)(wc * 64 + ni * 16 + cl) * 256 + kk * 32 + ql * 8);
#pragma unroll
    for (int mi = 0; mi < 4; ++mi) {
      bf16x8 afr = *(const bf16x8*)(xb + (size_t)(row0 + wr * 64 + mi * 16 + cl) * 256 + kk * 32 + ql * 8);
#pragma unroll
      for (int ni = 0; ni < 4; ++ni)
        acc[mi][ni] = __builtin_amdgcn_mfma_f32_16x16x32_bf16(afr, bfr[ni], acc[mi][ni], 0, 0, 0);
    }
  }
  // scale + write Vs (swizzled)
#pragma unroll
  for (int mi = 0; mi < 4; ++mi) {
    float sc[4];
#pragma unroll
    for (int r = 0; r < 4; ++r)
      sc[r] = ssum[(size_t)(row0 + wr * 64 + mi * 16 + ql * 4 + r) * 4 + wc];
#pragma unroll
    for (int ni = 0; ni < 4; ++ni) {
      int col = wc * 64 + ni * 16 + cl;
#pragma unroll
      for (int r = 0; r < 4; ++r) {
        int row = wr * 64 + mi * 16 + ql * 4 + r;
        int chunk = (col >> 3) ^ (row & 31);
        Vs[row * 256 + chunk * 8 + (col & 7)] = f2bf(acc[mi][ni][r] * sc[r]);
      }
    }
  }
  __syncthreads();
  // phase 2: O = Vs @ Wo^T
#pragma unroll
  for (int mi = 0; mi < 4; ++mi)
#pragma unroll
    for (int ni = 0; ni < 4; ++ni) acc[mi][ni] = (f32x4){0.f, 0.f, 0.f, 0.f};
#pragma unroll
  for (int kk = 0; kk < 8; ++kk) {
    bf16x8 bfr[4];
#pragma unroll
    for (int ni = 0; ni < 4; ++ni)
      bfr[ni] = *(const bf16x8*)(Wto + (size_t)(wc * 64 + ni * 16 + cl) * 256 + kk * 32 + ql * 8);
#pragma unroll
    for (int mi = 0; mi < 4; ++mi) {
      int lrow = wr * 64 + mi * 16 + cl;
      int chunk = (kk * 4 + ql) ^ (lrow & 31);
      bf16x8 afr = *(const bf16x8*)&Vs[lrow * 256 + chunk * 8];
#pragma unroll
      for (int ni = 0; ni < 4; ++ni)
        acc[mi][ni] = __builtin_amdgcn_mfma_f32_16x16x32_bf16(afr, bfr[ni], acc[mi][ni], 0, 0, 0);
    }
  }
  // epilogue: write ob bf16 + SE avg/max
  float lsum = 0.f, lmax = -3.4e38f;
#pragma unroll
  for (int mi = 0; mi < 4; ++mi)
#pragma unroll
    for (int ni = 0; ni < 4; ++ni) {
      int col = wc * 64 + ni * 16 + cl;
#pragma unroll
      for (int r = 0; r < 4; ++r) {
        int row = row0 + wr * 64 + mi * 16 + ql * 4 + r;
        float f = acc[mi][ni][r];
        ob[(size_t)row * 256 + col] = f2bf(f);
        lsum += f; lmax = fmaxf(lmax, f);
      }
    }
#pragma unroll
  for (int off = 32; off; off >>= 1) {
    lsum += __shfl_xor(lsum, off);
    lmax = fmaxf(lmax, __shfl_xor(lmax, off));
  }
  if (lane == 0) { redS[w] = lsum; redM[w] = lmax; }
  __syncthreads();
  if (tid < 2) {
    float s = redS[tid * 4] + redS[tid * 4 + 1] + redS[tid * 4 + 2] + redS[tid * 4 + 3];
    float m = fmaxf(fmaxf(redM[tid * 4], redM[tid * 4 + 1]),
                    fmaxf(redM[tid * 4 + 2], redM[tid * 4 + 3]));
    ravg[blockIdx.x * 2 + tid] = s * (1.f / 16384.f);
    rmax[blockIdx.x * 2 + tid] = m;
  }
}

// ---------------- SE MLP ----------------------------------------------------------
__global__ __launch_bounds__(256) void se_mlp(const float* __restrict__ ravg,
                                              const float* __restrict__ rmax,
                                              const float* __restrict__ fc1w,
                                              const float* __restrict__ fc1b,
                                              const float* __restrict__ fc2w,
                                              const float* __restrict__ fc2b,
                                              const float* __restrict__ bili,
                                              float* __restrict__ se) {
  int b = threadIdx.x;
  float avg[5], mx[5];
  for (int t = 0; t < 5; ++t) { avg[t] = ravg[b * 5 + t]; mx[t] = rmax[b * 5 + t]; }
  float w = bili[0];
  float h[25], s1[5], s2[5];
  for (int j = 0; j < 25; ++j) {
    float a = fc1b[j];
    for (int t = 0; t < 5; ++t) a += avg[t] * fc1w[t * 25 + j];
    h[j] = fmaxf(a, 0.f);
  }
  for (int t = 0; t < 5; ++t) {
    float a = fc2b[t];
    for (int j = 0; j < 25; ++j) a += h[j] * fc2w[j * 5 + t];
    s1[t] = 1.f / (1.f + __expf(-a));
  }
  for (int j = 0; j < 25; ++j) {
    float a = fc1b[j];
    for (int t = 0; t < 5; ++t) a += mx[t] * fc1w[t * 25 + j];
    h[j] = fmaxf(a, 0.f);
  }
  for (int t = 0; t < 5; ++t) {
    float a = fc2b[t];
    for (int j = 0; j < 25; ++j) a += h[j] * fc2w[j * 5 + t];
    s2[t] = 1.f / (1.f + __expf(-a));
  }
  for (int t = 0; t < 5; ++t) se[b * 5 + t] = (1.f - w) * s1[t] + w * s2[t];
}

// ---------------- final: out = bf16(o)*se[b,t] + bf16(x) --------------------------
__global__ __launch_bounds__(256) void final_kernel(const ushort_t* __restrict__ xb,
                                                    const float* __restrict__ se,
                                                    const ushort_t* __restrict__ ob,
                                                    float* __restrict__ out) {
  int i = blockIdx.x * 256 + threadIdx.x;      // float4 id, 5242880
  size_t j = (size_t)i * 4;
  int bt = (int)(j >> 14);
  float s = se[bt];
  uint2 uo = *(const uint2*)(ob + j);
  uint2 ux = *(const uint2*)(xb + j);
  float4 r = {bflo(uo.x) * s + bflo(ux.x), bfhi(uo.x) * s + bfhi(ux.x),
              bflo(uo.y) * s + bflo(ux.y), bfhi(uo.y) * s + bfhi(ux.y)};
  *(float4*)(out + j) = r;
}

extern "C" void kernel_launch(void* const* d_in, const int* in_sizes, int n_in,
                              void* d_out, int out_size, void* d_ws, size_t ws_size,
                              hipStream_t stream) {
  const float* x     = (const float*)d_in[0];
  const float* bias  = (const float*)d_in[1];
  const float* Wq    = (const float*)d_in[2];
  const float* Wv    = (const float*)d_in[3];
  const float* Wo    = (const float*)d_in[4];
  const float* u_t   = (const float*)d_in[5];
  const float* dis   = (const float*)d_in[6];
  const float* sigma = (const float*)d_in[7];
  const float* fc1w  = (const float*)d_in[8];
  const float* fc1b  = (const float*)d_in[9];
  const float* fc2w  = (const float*)d_in[10];
  const float* fc2b  = (const float*)d_in[11];
  const float* bili  = (const float*)d_in[12];
  float* out = (float*)d_out;

  // workspace layout (bytes), ~94.5 MB
  char* wsb = (char*)d_ws;
  ushort_t* xbuf = (ushort_t*)wsb;             wsb += 41943040;  // bf16(x), alive to end
  ushort_t* obuf = (ushort_t*)wsb;             wsb += 41943040;  // o bf16
  ushort_t* kb   = (ushort_t*)wsb;             wsb += 8388608;   // k bf16 [B,S,F]
  ushort_t* Wt   = (ushort_t*)wsb;             wsb += 393216;    // 3 x W^T bf16
  float*    ssum = (float*)wsb;                wsb += 1310720;
  float*    prior= (float*)wsb;                wsb += 81920;
  float*    bps  = (float*)wsb;                wsb += 327680;
  float*    ravg = (float*)wsb;                wsb += 5120;
  float*    rmax = (float*)wsb;                wsb += 5120;
  float*    se   = (float*)wsb;                wsb += 5120;

  convert_w<<<768, 256, 0, stream>>>(Wq, Wv, Wo, Wt);
  prior_kernel<<<80, 256, 0, stream>>>(dis, sigma, prior);
  bias_prior_sum<<<1280, 256, 0, stream>>>(bias, prior, bps);
  k_kernel<<<4096, 256, 0, stream>>>(x, u_t, kb, xbuf);
  qscore<<<1024, 256, 0, stream>>>(xbuf, Wt, kb, prior, bps, ssum);
  vo_gemm<<<640, 512, 0, stream>>>(xbuf, Wt + 65536, Wt + 131072, ssum, obuf, ravg, rmax);
  se_mlp<<<1, 256, 0, stream>>>(ravg, rmax, fc1w, fc1b, fc2w, fc2b, bili, se);
  final_kernel<<<20480, 256, 0, stream>>>(xbuf, se, obuf, out);
}

// Round 8
// 168.147 us; speedup vs baseline: 1.2290x; 1.2290x over previous
//
#include <hip/hip_runtime.h>

// B=256, T=5, S=64, F=256, H=4, Fh=64, N=H*B=1024, M=81920 rows of [.,256]

typedef unsigned short ushort_t;
typedef __attribute__((ext_vector_type(8))) short bf16x8;
typedef __attribute__((ext_vector_type(4))) float f32x4;

__device__ inline ushort_t f2bf(float f) {            // RNE f32 -> bf16
  unsigned u = __float_as_uint(f);
  return (ushort_t)((u + 0x7FFFu + ((u >> 16) & 1u)) >> 16);
}
__device__ inline float bflo(unsigned u) { return __uint_as_float(u << 16); }
__device__ inline float bfhi(unsigned u) { return __uint_as_float(u & 0xFFFF0000u); }

// ---------------- prior[t,s,c] ----------------------------------------------------
__global__ __launch_bounds__(256) void prior_kernel(const float* __restrict__ dis,
                                                    const float* __restrict__ sigma,
                                                    float* __restrict__ prior) {
  int i = blockIdx.x * 256 + threadIdx.x;
  if (i >= 5 * 64 * 64) return;
  int ts = i >> 6;
  float sg = sigma[ts];
  float d = dis[i];
  prior[i] = 0.3989422804014327f / sg * __expf(-d * d / (2.f * sg * sg));
}

// ---------------- bps[nb,t,c] = sum_s bias[nb,t,s,c]*prior[t,s,c] -----------------
__global__ __launch_bounds__(256) void bias_prior_sum(const float* __restrict__ bias,
                                                      const float* __restrict__ prior,
                                                      float* __restrict__ bps) {
  int blk = blockIdx.x;              // nb*5 + t, 1280 blocks
  int t = blk % 5, tid = threadIdx.x;
  const float* bp = bias + (size_t)blk * 4096;
  const float* pp = prior + t * 4096;
  int c = tid & 63, sg = tid >> 6;
  float sum = 0.f;
  for (int s = sg * 16; s < sg * 16 + 16; ++s)
    sum += bp[s * 64 + c] * pp[s * 64 + c];
  __shared__ float red[4][64];
  red[sg][c] = sum;
  __syncthreads();
  if (tid < 64)
    bps[(size_t)blk * 64 + tid] = red[0][tid] + red[1][tid] + red[2][tid] + red[3][tid];
}

// ---------------- k[b,s,f] = sum_t u[t]*x -> bf16;  xb = bf16(x) ------------------
__global__ __launch_bounds__(256) void k_kernel(const float* __restrict__ x,
                                                const float* __restrict__ u,
                                                ushort_t* __restrict__ kout,
                                                ushort_t* __restrict__ xb) {
  int i = blockIdx.x * 256 + threadIdx.x;      // float4 id, total 1048576
  size_t j = (size_t)i * 4;
  int b = (int)(j >> 14);
  int off = (int)(j & 16383);
  const float* xp = x + (size_t)b * 81920 + off;
  ushort_t* xq = xb + (size_t)b * 81920 + off;
  float u0 = u[0], u1 = u[1], u2 = u[2], u3 = u[3], u4 = u[4];
  float4 a0 = *(const float4*)(xp);
  float4 a1 = *(const float4*)(xp + 16384);
  float4 a2 = *(const float4*)(xp + 32768);
  float4 a3 = *(const float4*)(xp + 49152);
  float4 a4 = *(const float4*)(xp + 65536);
  ushort4 h0 = {f2bf(a0.x), f2bf(a0.y), f2bf(a0.z), f2bf(a0.w)};
  ushort4 h1 = {f2bf(a1.x), f2bf(a1.y), f2bf(a1.z), f2bf(a1.w)};
  ushort4 h2 = {f2bf(a2.x), f2bf(a2.y), f2bf(a2.z), f2bf(a2.w)};
  ushort4 h3 = {f2bf(a3.x), f2bf(a3.y), f2bf(a3.z), f2bf(a3.w)};
  ushort4 h4 = {f2bf(a4.x), f2bf(a4.y), f2bf(a4.z), f2bf(a4.w)};
  *(ushort4*)(xq) = h0;
  *(ushort4*)(xq + 16384) = h1;
  *(ushort4*)(xq + 32768) = h2;
  *(ushort4*)(xq + 49152) = h3;
  *(ushort4*)(xq + 65536) = h4;
  float4 r;
  r.x = u0 * a0.x + u1 * a1.x + u2 * a2.x + u3 * a3.x + u4 * a4.x;
  r.y = u0 * a0.y + u1 * a1.y + u2 * a2.y + u3 * a3.y + u4 * a4.y;
  r.z = u0 * a0.z + u1 * a1.z + u2 * a2.z + u3 * a3.z + u4 * a4.z;
  r.w = u0 * a0.w + u1 * a1.w + u2 * a2.w + u3 * a3.w + u4 * a4.w;
  ushort4 h = {f2bf(r.x), f2bf(r.y), f2bf(r.z), f2bf(r.w)};
  *(ushort4*)(kout + j) = h;
}

// ---------------- W^T convert: Wt[mat][n][k] = bf16(W[k][n]) ----------------------
__global__ __launch_bounds__(256) void convert_w(const float* __restrict__ Wq,
                                                 const float* __restrict__ Wv,
                                                 const float* __restrict__ Wo,
                                                 ushort_t* __restrict__ Wt) {
  int id = blockIdx.x * 256 + threadIdx.x;     // 196608
  if (id >= 196608) return;
  int mat = id >> 16, rem = id & 65535;
  int n = rem >> 8, k = rem & 255;
  const float* W = mat == 0 ? Wq : (mat == 1 ? Wv : Wo);
  Wt[id] = f2bf(W[k * 256 + n]);
}

// ---------------- MFMA GEMM: C_bf16[M,256] = A_bf16 @ Wt^T ------------------------
// SCALE: acc *= ssum[row*4 + col/64] (v-GEMM). SEEPI: fused SE avg/max (o-GEMM).
// BM=128, BN=256, BK=64, 512 threads = 8 waves (2 x 4), 16x16x32 bf16 MFMA.
// LDS tiles XOR-swizzled in 16B chunks: chunk c of row r stored at c^(r&7).
// NOTE: C may equal A (in-place). Safe: rows are block-exclusive and all global
// A reads complete before the epilogue stores (data-dep + barriers). C is NOT
// declared restrict for this reason.
template<int SCALE, int SEEPI>
__global__ __launch_bounds__(512, 4) void gemm_mfma(
    const ushort_t* __restrict__ A, const ushort_t* __restrict__ Wt,
    ushort_t* C, const float* __restrict__ ssum,
    float* __restrict__ ravg, float* __restrict__ rmax) {
  __shared__ __align__(16) ushort_t As_[128 * 64];
  __shared__ __align__(16) ushort_t Bs_[256 * 64];
  __shared__ float redS[8], redM[8];
  const int tid = threadIdx.x;
  const int lane = tid & 63;
  const int w = tid >> 6, wr = w >> 2, wc = w & 3;
  const int row0 = blockIdx.x * 128;
  const int cl = lane & 15, ql = lane >> 4, l7 = lane & 7;

  f32x4 acc[4][4];
#pragma unroll
  for (int i = 0; i < 4; ++i)
#pragma unroll
    for (int j = 0; j < 4; ++j) acc[i][j] = (f32x4){0.f, 0.f, 0.f, 0.f};

  for (int t = 0; t < 4; ++t) {
    const int k0 = t * 64;
    if (t) __syncthreads();
#pragma unroll
    for (int l = 0; l < 2; ++l) {              // A: 1024 16B chunks
      int i = l * 512 + tid;
      int r = i >> 3, c = i & 7;
      uint4 v = *(const uint4*)(A + (size_t)(row0 + r) * 256 + k0 + c * 8);
      *(uint4*)&As_[r * 64 + ((c ^ (r & 7)) * 8)] = v;
    }
#pragma unroll
    for (int l = 0; l < 4; ++l) {              // B: 2048 16B chunks
      int i = l * 512 + tid;
      int n = i >> 3, c = i & 7;
      uint4 v = *(const uint4*)(Wt + (size_t)n * 256 + k0 + c * 8);
      *(uint4*)&Bs_[n * 64 + ((c ^ (n & 7)) * 8)] = v;
    }
    __syncthreads();
#pragma unroll
    for (int kk = 0; kk < 2; ++kk) {
      const int offk = (((kk << 2) | ql) ^ l7) * 8;
      bf16x8 bfr[4], afr[4];
#pragma unroll
      for (int ni = 0; ni < 4; ++ni)
        bfr[ni] = *(const bf16x8*)&Bs_[(wc * 64 + ni * 16 + cl) * 64 + offk];
#pragma unroll
      for (int mi = 0; mi < 4; ++mi)
        afr[mi] = *(const bf16x8*)&As_[(wr * 64 + mi * 16 + cl) * 64 + offk];
#pragma unroll
      for (int mi = 0; mi < 4; ++mi)
#pragma unroll
        for (int ni = 0; ni < 4; ++ni)
          acc[mi][ni] = __builtin_amdgcn_mfma_f32_16x16x32_bf16(afr[mi], bfr[ni], acc[mi][ni], 0, 0, 0);
    }
  }
  // epilogue: D row = wr*64+mi*16+ql*4+r, col = wc*64+ni*16+cl
  float lsum = 0.f, lmax = -3.4e38f;
#pragma unroll
  for (int mi = 0; mi < 4; ++mi) {
    float sc[4];
    if (SCALE) {
#pragma unroll
      for (int r = 0; r < 4; ++r)
        sc[r] = ssum[(size_t)(row0 + wr * 64 + mi * 16 + ql * 4 + r) * 4 + wc];
    }
#pragma unroll
    for (int ni = 0; ni < 4; ++ni) {
      int col = wc * 64 + ni * 16 + cl;
      f32x4 v = acc[mi][ni];
#pragma unroll
      for (int r = 0; r < 4; ++r) {
        int row = row0 + wr * 64 + mi * 16 + ql * 4 + r;
        float f = v[r];
        if (SCALE) f *= sc[r];
        C[(size_t)row * 256 + col] = f2bf(f);
        if (SEEPI) { lsum += f; lmax = fmaxf(lmax, f); }
      }
    }
  }
  if (SEEPI) {
#pragma unroll
    for (int off = 32; off; off >>= 1) {
      lsum += __shfl_xor(lsum, off);
      lmax = fmaxf(lmax, __shfl_xor(lmax, off));
    }
    if (lane == 0) { redS[w] = lsum; redM[w] = lmax; }
    __syncthreads();
    if (tid < 2) {                             // group bt = row0/64 + tid (tid==wr)
      float s = redS[tid * 4] + redS[tid * 4 + 1] + redS[tid * 4 + 2] + redS[tid * 4 + 3];
      float m = fmaxf(fmaxf(redM[tid * 4], redM[tid * 4 + 1]),
                      fmaxf(redM[tid * 4 + 2], redM[tid * 4 + 3]));
      ravg[blockIdx.x * 2 + tid] = s * (1.f / 16384.f);
      rmax[blockIdx.x * 2 + tid] = m;
    }
  }
}

// ---------------- score via MFMA ---------------------------------------------------
// ssum[n,t,c] = sum_s sigmoid(qk/8)*prior[t,s,c] - bps[n%256,t,c]
// Block = one n, 4 waves; wave w owns col-strip c in [w*16, w*16+16).
__global__ __launch_bounds__(256) void score_mfma(const ushort_t* __restrict__ q,
                                                  const ushort_t* __restrict__ kbuf,
                                                  const float* __restrict__ prior,
                                                  const float* __restrict__ bps,
                                                  float* __restrict__ ssum) {
  const int n = blockIdx.x;
  const int tid = threadIdx.x;
  const int lane = tid & 63;
  const int w = tid >> 6;
  const int cl = lane & 15, ql = lane >> 4;
  const int nb = n & 255;
  const int c = w * 16 + cl;
  const ushort_t* kb = kbuf + (size_t)(n >> 2) * 16384 + (n & 3) * 64;
  bf16x8 kfr0 = *(const bf16x8*)(kb + c * 256 + ql * 8);
  bf16x8 kfr1 = *(const bf16x8*)(kb + c * 256 + ql * 8 + 32);
  for (int t = 0; t < 5; ++t) {
    const ushort_t* qt = q + (size_t)n * 20480 + t * 4096;
    f32x4 acc[4];
#pragma unroll
    for (int si = 0; si < 4; ++si) {
      bf16x8 a0 = *(const bf16x8*)(qt + (si * 16 + cl) * 64 + ql * 8);
      bf16x8 a1 = *(const bf16x8*)(qt + (si * 16 + cl) * 64 + ql * 8 + 32);
      f32x4 z = (f32x4){0.f, 0.f, 0.f, 0.f};
      z = __builtin_amdgcn_mfma_f32_16x16x32_bf16(a0, kfr0, z, 0, 0, 0);
      z = __builtin_amdgcn_mfma_f32_16x16x32_bf16(a1, kfr1, z, 0, 0, 0);
      acc[si] = z;
    }
    const float* pp = prior + t * 4096;
    float colsum = 0.f;
#pragma unroll
    for (int si = 0; si < 4; ++si) {
#pragma unroll
      for (int r = 0; r < 4; ++r) {
        int s = si * 16 + ql * 4 + r;
        float sg = 1.f / (1.f + __expf(-acc[si][r] * 0.125f));
        colsum += sg * pp[s * 64 + c];
      }
    }
    colsum += __shfl_xor(colsum, 16);
    colsum += __shfl_xor(colsum, 32);
    if (ql == 0)
      ssum[(size_t)n * 320 + t * 64 + c] = colsum - bps[((size_t)nb * 5 + t) * 64 + c];
  }
}

// ---------------- SE MLP ----------------------------------------------------------
__global__ __launch_bounds__(256) void se_mlp(const float* __restrict__ ravg,
                                              const float* __restrict__ rmax,
                                              const float* __restrict__ fc1w,
                                              const float* __restrict__ fc1b,
                                              const float* __restrict__ fc2w,
                                              const float* __restrict__ fc2b,
                                              const float* __restrict__ bili,
                                              float* __restrict__ se) {
  int b = threadIdx.x;
  float avg[5], mx[5];
  for (int t = 0; t < 5; ++t) { avg[t] = ravg[b * 5 + t]; mx[t] = rmax[b * 5 + t]; }
  float w = bili[0];
  float h[25], s1[5], s2[5];
  for (int j = 0; j < 25; ++j) {
    float a = fc1b[j];
    for (int t = 0; t < 5; ++t) a += avg[t] * fc1w[t * 25 + j];
    h[j] = fmaxf(a, 0.f);
  }
  for (int t = 0; t < 5; ++t) {
    float a = fc2b[t];
    for (int j = 0; j < 25; ++j) a += h[j] * fc2w[j * 5 + t];
    s1[t] = 1.f / (1.f + __expf(-a));
  }
  for (int j = 0; j < 25; ++j) {
    float a = fc1b[j];
    for (int t = 0; t < 5; ++t) a += mx[t] * fc1w[t * 25 + j];
    h[j] = fmaxf(a, 0.f);
  }
  for (int t = 0; t < 5; ++t) {
    float a = fc2b[t];
    for (int j = 0; j < 25; ++j) a += h[j] * fc2w[j * 5 + t];
    s2[t] = 1.f / (1.f + __expf(-a));
  }
  for (int t = 0; t < 5; ++t) se[b * 5 + t] = (1.f - w) * s1[t] + w * s2[t];
}

// ---------------- final: out = bf16(o)*se[b,t] + bf16(x) --------------------------
__global__ __launch_bounds__(256) void final_kernel(const ushort_t* __restrict__ xb,
                                                    const float* __restrict__ se,
                                                    const ushort_t* __restrict__ ob,
                                                    float* __restrict__ out) {
  int i = blockIdx.x * 256 + threadIdx.x;      // float4 id, 5242880
  size_t j = (size_t)i * 4;
  int bt = (int)(j >> 14);
  float s = se[bt];
  uint2 uo = *(const uint2*)(ob + j);
  uint2 ux = *(const uint2*)(xb + j);
  float4 r = {bflo(uo.x) * s + bflo(ux.x), bfhi(uo.x) * s + bfhi(ux.x),
              bflo(uo.y) * s + bflo(ux.y), bfhi(uo.y) * s + bfhi(ux.y)};
  *(float4*)(out + j) = r;
}

extern "C" void kernel_launch(void* const* d_in, const int* in_sizes, int n_in,
                              void* d_out, int out_size, void* d_ws, size_t ws_size,
                              hipStream_t stream) {
  const float* x     = (const float*)d_in[0];
  const float* bias  = (const float*)d_in[1];
  const float* Wq    = (const float*)d_in[2];
  const float* Wv    = (const float*)d_in[3];
  const float* Wo    = (const float*)d_in[4];
  const float* u_t   = (const float*)d_in[5];
  const float* dis   = (const float*)d_in[6];
  const float* sigma = (const float*)d_in[7];
  const float* fc1w  = (const float*)d_in[8];
  const float* fc1b  = (const float*)d_in[9];
  const float* fc2w  = (const float*)d_in[10];
  const float* fc2b  = (const float*)d_in[11];
  const float* bili  = (const float*)d_in[12];
  float* out = (float*)d_out;

  // workspace layout (bytes), ~94.5 MB. qvb carries q -> v*ssum -> o (in place).
  char* wsb = (char*)d_ws;
  ushort_t* xbuf = (ushort_t*)wsb;             wsb += 41943040;  // bf16(x), alive to end
  ushort_t* qvb  = (ushort_t*)wsb;             wsb += 41943040;  // q / v*s / o
  ushort_t* kb   = (ushort_t*)wsb;             wsb += 8388608;   // k bf16 [B,S,F]
  ushort_t* Wt   = (ushort_t*)wsb;             wsb += 393216;    // 3 x W^T bf16
  float*    ssum = (float*)wsb;                wsb += 1310720;
  float*    prior= (float*)wsb;                wsb += 81920;
  float*    bps  = (float*)wsb;                wsb += 327680;
  float*    ravg = (float*)wsb;                wsb += 5120;
  float*    rmax = (float*)wsb;                wsb += 5120;
  float*    se   = (float*)wsb;                wsb += 5120;

  convert_w<<<768, 256, 0, stream>>>(Wq, Wv, Wo, Wt);
  prior_kernel<<<80, 256, 0, stream>>>(dis, sigma, prior);
  bias_prior_sum<<<1280, 256, 0, stream>>>(bias, prior, bps);
  k_kernel<<<4096, 256, 0, stream>>>(x, u_t, kb, xbuf);
  // q = xb @ Wq
  gemm_mfma<0, 0><<<640, 512, 0, stream>>>(xbuf, Wt, qvb, nullptr, nullptr, nullptr);
  score_mfma<<<1024, 256, 0, stream>>>(qvb, kb, prior, bps, ssum);
  // v = xb @ Wv, scaled by ssum in epilogue (overwrites q)
  gemm_mfma<1, 0><<<640, 512, 0, stream>>>(xbuf, Wt + 65536, qvb, ssum, nullptr, nullptr);
  // o = (v.*s) @ Wo -> qvb IN PLACE, fused SE avg/max
  gemm_mfma<0, 1><<<640, 512, 0, stream>>>(qvb, Wt + 131072, qvb, nullptr, ravg, rmax);
  se_mlp<<<1, 256, 0, stream>>>(ravg, rmax, fc1w, fc1b, fc2w, fc2b, bili, se);
  final_kernel<<<20480, 256, 0, stream>>>(xbuf, se, qvb, out);
}

// Round 9
// 166.843 us; speedup vs baseline: 1.2386x; 1.0078x over previous
//
#include <hip/hip_runtime.h>

// B=256, T=5, S=64, F=256, H=4, Fh=64, N=H*B=1024, M=81920 rows of [.,256]

typedef unsigned short ushort_t;
typedef __attribute__((ext_vector_type(8))) short bf16x8;
typedef __attribute__((ext_vector_type(4))) float f32x4;

__device__ inline ushort_t f2bf(float f) {            // RNE f32 -> bf16
  unsigned u = __float_as_uint(f);
  return (ushort_t)((u + 0x7FFFu + ((u >> 16) & 1u)) >> 16);
}
__device__ inline float bflo(unsigned u) { return __uint_as_float(u << 16); }
__device__ inline float bfhi(unsigned u) { return __uint_as_float(u & 0xFFFF0000u); }

// ---------------- fused prep: convert_w | prior | bias_prior_sum | k/xb -----------
// blocks [0,768): Wt[mat][n][k] = bf16(W[k][n])
// blocks [768,848): prior[t,s,c]
// blocks [848,2128): bps[nb,t,c] = sum_s bias*prior (prior recomputed inline)
// blocks [2128,6224): k[b,s,f] = sum_t u[t]*x -> bf16, and xb = bf16(x)
__global__ __launch_bounds__(256) void prep_kernel(
    const float* __restrict__ x, const float* __restrict__ u,
    const float* __restrict__ Wq, const float* __restrict__ Wv,
    const float* __restrict__ Wo, const float* __restrict__ dis,
    const float* __restrict__ sigma, const float* __restrict__ bias,
    ushort_t* __restrict__ Wt, float* __restrict__ prior,
    float* __restrict__ bps, ushort_t* __restrict__ kout,
    ushort_t* __restrict__ xb) {
  __shared__ float red[4][64];
  const int blk = blockIdx.x, tid = threadIdx.x;
  if (blk < 768) {
    int id = blk * 256 + tid;                  // 196608
    int mat = id >> 16, rem = id & 65535;
    int n = rem >> 8, k = rem & 255;
    const float* W = mat == 0 ? Wq : (mat == 1 ? Wv : Wo);
    Wt[id] = f2bf(W[k * 256 + n]);
  } else if (blk < 848) {
    int i = (blk - 768) * 256 + tid;           // 20480
    int ts = i >> 6;
    float sg = sigma[ts];
    float d = dis[i];
    prior[i] = 0.3989422804014327f / sg * __expf(-d * d / (2.f * sg * sg));
  } else if (blk < 2128) {
    int b2 = blk - 848;                        // nb*5 + t, 1280 blocks
    int t = b2 % 5;
    const float* bp = bias + (size_t)b2 * 4096;
    int c = tid & 63, sg_ = tid >> 6;
    float sum = 0.f;
    for (int s = sg_ * 16; s < sg_ * 16 + 16; ++s) {
      float sgm = sigma[t * 64 + s];
      float d = dis[t * 4096 + s * 64 + c];
      float pr = 0.3989422804014327f / sgm * __expf(-d * d / (2.f * sgm * sgm));
      sum += bp[s * 64 + c] * pr;
    }
    red[sg_][c] = sum;
    __syncthreads();
    if (tid < 64)
      bps[(size_t)b2 * 64 + tid] = red[0][tid] + red[1][tid] + red[2][tid] + red[3][tid];
  } else {
    int i = (blk - 2128) * 256 + tid;          // float4 id, 1048576
    size_t j = (size_t)i * 4;
    int b = (int)(j >> 14);
    int off = (int)(j & 16383);
    const float* xp = x + (size_t)b * 81920 + off;
    ushort_t* xq = xb + (size_t)b * 81920 + off;
    float u0 = u[0], u1 = u[1], u2 = u[2], u3 = u[3], u4 = u[4];
    float4 a0 = *(const float4*)(xp);
    float4 a1 = *(const float4*)(xp + 16384);
    float4 a2 = *(const float4*)(xp + 32768);
    float4 a3 = *(const float4*)(xp + 49152);
    float4 a4 = *(const float4*)(xp + 65536);
    ushort4 h0 = {f2bf(a0.x), f2bf(a0.y), f2bf(a0.z), f2bf(a0.w)};
    ushort4 h1 = {f2bf(a1.x), f2bf(a1.y), f2bf(a1.z), f2bf(a1.w)};
    ushort4 h2 = {f2bf(a2.x), f2bf(a2.y), f2bf(a2.z), f2bf(a2.w)};
    ushort4 h3 = {f2bf(a3.x), f2bf(a3.y), f2bf(a3.z), f2bf(a3.w)};
    ushort4 h4 = {f2bf(a4.x), f2bf(a4.y), f2bf(a4.z), f2bf(a4.w)};
    *(ushort4*)(xq) = h0;
    *(ushort4*)(xq + 16384) = h1;
    *(ushort4*)(xq + 32768) = h2;
    *(ushort4*)(xq + 49152) = h3;
    *(ushort4*)(xq + 65536) = h4;
    float4 r;
    r.x = u0 * a0.x + u1 * a1.x + u2 * a2.x + u3 * a3.x + u4 * a4.x;
    r.y = u0 * a0.y + u1 * a1.y + u2 * a2.y + u3 * a3.y + u4 * a4.y;
    r.z = u0 * a0.z + u1 * a1.z + u2 * a2.z + u3 * a3.z + u4 * a4.z;
    r.w = u0 * a0.w + u1 * a1.w + u2 * a2.w + u3 * a3.w + u4 * a4.w;
    ushort4 h = {f2bf(r.x), f2bf(r.y), f2bf(r.z), f2bf(r.w)};
    *(ushort4*)(kout + j) = h;
  }
}

// ---------------- MFMA GEMM: C_bf16[M,256] = A_bf16 @ Wt^T ------------------------
// SCALE: acc *= ssum[row*4 + col/64] (v-GEMM). SEEPI: fused SE avg/max (o-GEMM).
// BM=128, BN=256, BK=64, 512 threads = 8 waves (2 x 4), 16x16x32 bf16 MFMA.
// LDS tiles XOR-swizzled in 16B chunks: chunk c of row r stored at c^(r&7).
// NOTE: C may equal A (in-place). Safe: rows are block-exclusive and all global
// A reads complete before the epilogue stores. C is NOT declared restrict.
template<int SCALE, int SEEPI>
__global__ __launch_bounds__(512, 4) void gemm_mfma(
    const ushort_t* __restrict__ A, const ushort_t* __restrict__ Wt,
    ushort_t* C, const float* __restrict__ ssum,
    float* __restrict__ ravg, float* __restrict__ rmax) {
  __shared__ __align__(16) ushort_t As_[128 * 64];
  __shared__ __align__(16) ushort_t Bs_[256 * 64];
  __shared__ float redS[8], redM[8];
  const int tid = threadIdx.x;
  const int lane = tid & 63;
  const int w = tid >> 6, wr = w >> 2, wc = w & 3;
  const int row0 = blockIdx.x * 128;
  const int cl = lane & 15, ql = lane >> 4, l7 = lane & 7;

  f32x4 acc[4][4];
#pragma unroll
  for (int i = 0; i < 4; ++i)
#pragma unroll
    for (int j = 0; j < 4; ++j) acc[i][j] = (f32x4){0.f, 0.f, 0.f, 0.f};

  for (int t = 0; t < 4; ++t) {
    const int k0 = t * 64;
    if (t) __syncthreads();
#pragma unroll
    for (int l = 0; l < 2; ++l) {              // A: 1024 16B chunks
      int i = l * 512 + tid;
      int r = i >> 3, c = i & 7;
      uint4 v = *(const uint4*)(A + (size_t)(row0 + r) * 256 + k0 + c * 8);
      *(uint4*)&As_[r * 64 + ((c ^ (r & 7)) * 8)] = v;
    }
#pragma unroll
    for (int l = 0; l < 4; ++l) {              // B: 2048 16B chunks
      int i = l * 512 + tid;
      int n = i >> 3, c = i & 7;
      uint4 v = *(const uint4*)(Wt + (size_t)n * 256 + k0 + c * 8);
      *(uint4*)&Bs_[n * 64 + ((c ^ (n & 7)) * 8)] = v;
    }
    __syncthreads();
#pragma unroll
    for (int kk = 0; kk < 2; ++kk) {
      const int offk = (((kk << 2) | ql) ^ l7) * 8;
      bf16x8 bfr[4], afr[4];
#pragma unroll
      for (int ni = 0; ni < 4; ++ni)
        bfr[ni] = *(const bf16x8*)&Bs_[(wc * 64 + ni * 16 + cl) * 64 + offk];
#pragma unroll
      for (int mi = 0; mi < 4; ++mi)
        afr[mi] = *(const bf16x8*)&As_[(wr * 64 + mi * 16 + cl) * 64 + offk];
#pragma unroll
      for (int mi = 0; mi < 4; ++mi)
#pragma unroll
        for (int ni = 0; ni < 4; ++ni)
          acc[mi][ni] = __builtin_amdgcn_mfma_f32_16x16x32_bf16(afr[mi], bfr[ni], acc[mi][ni], 0, 0, 0);
    }
  }
  // epilogue: D row = wr*64+mi*16+ql*4+r, col = wc*64+ni*16+cl
  float lsum = 0.f, lmax = -3.4e38f;
#pragma unroll
  for (int mi = 0; mi < 4; ++mi) {
    float sc[4];
    if (SCALE) {
#pragma unroll
      for (int r = 0; r < 4; ++r)
        sc[r] = ssum[(size_t)(row0 + wr * 64 + mi * 16 + ql * 4 + r) * 4 + wc];
    }
#pragma unroll
    for (int ni = 0; ni < 4; ++ni) {
      int col = wc * 64 + ni * 16 + cl;
      f32x4 v = acc[mi][ni];
#pragma unroll
      for (int r = 0; r < 4; ++r) {
        int row = row0 + wr * 64 + mi * 16 + ql * 4 + r;
        float f = v[r];
        if (SCALE) f *= sc[r];
        C[(size_t)row * 256 + col] = f2bf(f);
        if (SEEPI) { lsum += f; lmax = fmaxf(lmax, f); }
      }
    }
  }
  if (SEEPI) {
#pragma unroll
    for (int off = 32; off; off >>= 1) {
      lsum += __shfl_xor(lsum, off);
      lmax = fmaxf(lmax, __shfl_xor(lmax, off));
    }
    if (lane == 0) { redS[w] = lsum; redM[w] = lmax; }
    __syncthreads();
    if (tid < 2) {                             // group bt = row0/64 + tid
      float s = redS[tid * 4] + redS[tid * 4 + 1] + redS[tid * 4 + 2] + redS[tid * 4 + 3];
      float m = fmaxf(fmaxf(redM[tid * 4], redM[tid * 4 + 1]),
                      fmaxf(redM[tid * 4 + 2], redM[tid * 4 + 3]));
      ravg[blockIdx.x * 2 + tid] = s * (1.f / 16384.f);
      rmax[blockIdx.x * 2 + tid] = m;
    }
  }
}

// ---------------- score via MFMA ---------------------------------------------------
// ssum[n,t,c] = sum_s sigmoid(qk/8)*prior[t,s,c] - bps[n%256,t,c]
__global__ __launch_bounds__(256) void score_mfma(const ushort_t* __restrict__ q,
                                                  const ushort_t* __restrict__ kbuf,
                                                  const float* __restrict__ prior,
                                                  const float* __restrict__ bps,
                                                  float* __restrict__ ssum) {
  const int n = blockIdx.x;
  const int tid = threadIdx.x;
  const int lane = tid & 63;
  const int w = tid >> 6;
  const int cl = lane & 15, ql = lane >> 4;
  const int nb = n & 255;
  const int c = w * 16 + cl;
  const ushort_t* kb = kbuf + (size_t)(n >> 2) * 16384 + (n & 3) * 64;
  bf16x8 kfr0 = *(const bf16x8*)(kb + c * 256 + ql * 8);
  bf16x8 kfr1 = *(const bf16x8*)(kb + c * 256 + ql * 8 + 32);
  for (int t = 0; t < 5; ++t) {
    const ushort_t* qt = q + (size_t)n * 20480 + t * 4096;
    f32x4 acc[4];
#pragma unroll
    for (int si = 0; si < 4; ++si) {
      bf16x8 a0 = *(const bf16x8*)(qt + (si * 16 + cl) * 64 + ql * 8);
      bf16x8 a1 = *(const bf16x8*)(qt + (si * 16 + cl) * 64 + ql * 8 + 32);
      f32x4 z = (f32x4){0.f, 0.f, 0.f, 0.f};
      z = __builtin_amdgcn_mfma_f32_16x16x32_bf16(a0, kfr0, z, 0, 0, 0);
      z = __builtin_amdgcn_mfma_f32_16x16x32_bf16(a1, kfr1, z, 0, 0, 0);
      acc[si] = z;
    }
    const float* pp = prior + t * 4096;
    float colsum = 0.f;
#pragma unroll
    for (int si = 0; si < 4; ++si) {
#pragma unroll
      for (int r = 0; r < 4; ++r) {
        int s = si * 16 + ql * 4 + r;
        float sg = 1.f / (1.f + __expf(-acc[si][r] * 0.125f));
        colsum += sg * pp[s * 64 + c];
      }
    }
    colsum += __shfl_xor(colsum, 16);
    colsum += __shfl_xor(colsum, 32);
    if (ql == 0)
      ssum[(size_t)n * 320 + t * 64 + c] = colsum - bps[((size_t)nb * 5 + t) * 64 + c];
  }
}

// ---------------- final: out = bf16(o)*se[b,t] + bf16(x), se computed inline ------
// Each block covers 1024 consecutive floats => exactly one (b,t) group.
__global__ __launch_bounds__(256) void final_kernel(
    const ushort_t* __restrict__ xb, const ushort_t* __restrict__ ob,
    const float* __restrict__ ravg, const float* __restrict__ rmax,
    const float* __restrict__ fc1w, const float* __restrict__ fc1b,
    const float* __restrict__ fc2w, const float* __restrict__ fc2b,
    const float* __restrict__ bili, float* __restrict__ out) {
  __shared__ float sse;
  int i = blockIdx.x * 256 + threadIdx.x;      // float4 id, 5242880
  size_t j = (size_t)i * 4;
  int bt = (int)(j >> 14);
  uint2 uo = *(const uint2*)(ob + j);          // issue loads before serial SE
  uint2 ux = *(const uint2*)(xb + j);
  if (threadIdx.x == 0) {
    int b = bt / 5, t = bt % 5;
    float avg[5], mx[5];
    for (int tt = 0; tt < 5; ++tt) { avg[tt] = ravg[b * 5 + tt]; mx[tt] = rmax[b * 5 + tt]; }
    float w = bili[0];
    float s12[2];
    for (int p = 0; p < 2; ++p) {
      const float* in = p == 0 ? avg : mx;
      float a = fc2b[t];
      for (int jj = 0; jj < 25; ++jj) {
        float hh = fc1b[jj];
        for (int tt = 0; tt < 5; ++tt) hh += in[tt] * fc1w[tt * 25 + jj];
        a += fmaxf(hh, 0.f) * fc2w[jj * 5 + t];
      }
      s12[p] = 1.f / (1.f + __expf(-a));
    }
    sse = (1.f - w) * s12[0] + w * s12[1];
  }
  __syncthreads();
  float s = sse;
  float4 r = {bflo(uo.x) * s + bflo(ux.x), bfhi(uo.x) * s + bfhi(ux.x),
              bflo(uo.y) * s + bflo(ux.y), bfhi(uo.y) * s + bfhi(ux.y)};
  *(float4*)(out + j) = r;
}

extern "C" void kernel_launch(void* const* d_in, const int* in_sizes, int n_in,
                              void* d_out, int out_size, void* d_ws, size_t ws_size,
                              hipStream_t stream) {
  const float* x     = (const float*)d_in[0];
  const float* bias  = (const float*)d_in[1];
  const float* Wq    = (const float*)d_in[2];
  const float* Wv    = (const float*)d_in[3];
  const float* Wo    = (const float*)d_in[4];
  const float* u_t   = (const float*)d_in[5];
  const float* dis   = (const float*)d_in[6];
  const float* sigma = (const float*)d_in[7];
  const float* fc1w  = (const float*)d_in[8];
  const float* fc1b  = (const float*)d_in[9];
  const float* fc2w  = (const float*)d_in[10];
  const float* fc2b  = (const float*)d_in[11];
  const float* bili  = (const float*)d_in[12];
  float* out = (float*)d_out;

  // workspace layout (bytes), ~94.5 MB. qvb carries q -> v*ssum -> o (in place).
  char* wsb = (char*)d_ws;
  ushort_t* xbuf = (ushort_t*)wsb;             wsb += 41943040;  // bf16(x), alive to end
  ushort_t* qvb  = (ushort_t*)wsb;             wsb += 41943040;  // q / v*s / o
  ushort_t* kb   = (ushort_t*)wsb;             wsb += 8388608;   // k bf16 [B,S,F]
  ushort_t* Wt   = (ushort_t*)wsb;             wsb += 393216;    // 3 x W^T bf16
  float*    ssum = (float*)wsb;                wsb += 1310720;
  float*    prior= (float*)wsb;                wsb += 81920;
  float*    bps  = (float*)wsb;                wsb += 327680;
  float*    ravg = (float*)wsb;                wsb += 5120;
  float*    rmax = (float*)wsb;                wsb += 5120;

  // 1) fused prep: Wt | prior | bps | (k, xb)
  prep_kernel<<<6224, 256, 0, stream>>>(x, u_t, Wq, Wv, Wo, dis, sigma, bias,
                                        Wt, prior, bps, kb, xbuf);
  // 2) q = xb @ Wq
  gemm_mfma<0, 0><<<640, 512, 0, stream>>>(xbuf, Wt, qvb, nullptr, nullptr, nullptr);
  // 3) score
  score_mfma<<<1024, 256, 0, stream>>>(qvb, kb, prior, bps, ssum);
  // 4) v = xb @ Wv, scaled by ssum in epilogue (overwrites q)
  gemm_mfma<1, 0><<<640, 512, 0, stream>>>(xbuf, Wt + 65536, qvb, ssum, nullptr, nullptr);
  // 5) o = (v.*s) @ Wo -> qvb IN PLACE, fused SE avg/max
  gemm_mfma<0, 1><<<640, 512, 0, stream>>>(qvb, Wt + 131072, qvb, nullptr, ravg, rmax);
  // 6) final with inline SE MLP
  final_kernel<<<20480, 256, 0, stream>>>(xbuf, qvb, ravg, rmax,
                                          fc1w, fc1b, fc2w, fc2b, bili, out);
}

// Round 10
// 156.249 us; speedup vs baseline: 1.3226x; 1.0678x over previous
//
#include <hip/hip_runtime.h>

// B=256, T=5, S=64, F=256, H=4, Fh=64, N=H*B=1024, M=81920 rows of [.,256]

typedef unsigned short ushort_t;
typedef __attribute__((ext_vector_type(8))) short bf16x8;
typedef __attribute__((ext_vector_type(4))) float f32x4;

__device__ inline ushort_t f2bf(float f) {            // RNE f32 -> bf16
  unsigned u = __float_as_uint(f);
  return (ushort_t)((u + 0x7FFFu + ((u >> 16) & 1u)) >> 16);
}
__device__ inline float bflo(unsigned u) { return __uint_as_float(u << 16); }
__device__ inline float bfhi(unsigned u) { return __uint_as_float(u & 0xFFFF0000u); }
__device__ inline uint4 pack8(float4 a, float4 b) {   // 8 f32 -> 8 bf16 in uint4
  uint4 r;
  r.x = (unsigned)f2bf(a.x) | ((unsigned)f2bf(a.y) << 16);
  r.y = (unsigned)f2bf(a.z) | ((unsigned)f2bf(a.w) << 16);
  r.z = (unsigned)f2bf(b.x) | ((unsigned)f2bf(b.y) << 16);
  r.w = (unsigned)f2bf(b.z) | ((unsigned)f2bf(b.w) << 16);
  return r;
}

// ---------------- fused prep: convert_w | prior | bias_prior_sum | k/xb -----------
// blocks [0,768): Wt[mat][n][k] = bf16(W[k][n])
// blocks [768,848): prior[t,s,c]
// blocks [848,2128): bps[nb,t,c] = sum_s bias*prior (prior recomputed inline)
// blocks [2128,4176): k[b,s,f] = sum_t u[t]*x -> bf16, and xb = bf16(x); 8 f/thread
__global__ __launch_bounds__(256) void prep_kernel(
    const float* __restrict__ x, const float* __restrict__ u,
    const float* __restrict__ Wq, const float* __restrict__ Wv,
    const float* __restrict__ Wo, const float* __restrict__ dis,
    const float* __restrict__ sigma, const float* __restrict__ bias,
    ushort_t* __restrict__ Wt, float* __restrict__ prior,
    float* __restrict__ bps, ushort_t* __restrict__ kout,
    ushort_t* __restrict__ xb) {
  __shared__ float red[4][64];
  const int blk = blockIdx.x, tid = threadIdx.x;
  if (blk < 768) {
    int id = blk * 256 + tid;                  // 196608
    int mat = id >> 16, rem = id & 65535;
    int n = rem >> 8, k = rem & 255;
    const float* W = mat == 0 ? Wq : (mat == 1 ? Wv : Wo);
    Wt[id] = f2bf(W[k * 256 + n]);
  } else if (blk < 848) {
    int i = (blk - 768) * 256 + tid;           // 20480
    int ts = i >> 6;
    float sg = sigma[ts];
    float d = dis[i];
    prior[i] = 0.3989422804014327f / sg * __expf(-d * d / (2.f * sg * sg));
  } else if (blk < 2128) {
    int b2 = blk - 848;                        // nb*5 + t, 1280 blocks
    int t = b2 % 5;
    const float* bp = bias + (size_t)b2 * 4096;
    int c = tid & 63, sg_ = tid >> 6;
    float sum = 0.f;
    for (int s = sg_ * 16; s < sg_ * 16 + 16; ++s) {
      float sgm = sigma[t * 64 + s];
      float d = dis[t * 4096 + s * 64 + c];
      float pr = 0.3989422804014327f / sgm * __expf(-d * d / (2.f * sgm * sgm));
      sum += bp[s * 64 + c] * pr;
    }
    red[sg_][c] = sum;
    __syncthreads();
    if (tid < 64)
      bps[(size_t)b2 * 64 + tid] = red[0][tid] + red[1][tid] + red[2][tid] + red[3][tid];
  } else {
    int i = (blk - 2128) * 256 + tid;          // 8-float id, 524288 total
    size_t j = (size_t)i * 8;
    int b = (int)(j >> 14);
    int off = (int)(j & 16383);
    const float* xp = x + (size_t)b * 81920 + off;
    ushort_t* xq = xb + (size_t)b * 81920 + off;
    float u0 = u[0], u1 = u[1], u2 = u[2], u3 = u[3], u4 = u[4];
    float4 lo[5], hi[5];
#pragma unroll
    for (int t = 0; t < 5; ++t) {
      lo[t] = *(const float4*)(xp + t * 16384);
      hi[t] = *(const float4*)(xp + t * 16384 + 4);
    }
#pragma unroll
    for (int t = 0; t < 5; ++t)
      *(uint4*)(xq + t * 16384) = pack8(lo[t], hi[t]);
    float4 rl, rh;
    rl.x = u0*lo[0].x + u1*lo[1].x + u2*lo[2].x + u3*lo[3].x + u4*lo[4].x;
    rl.y = u0*lo[0].y + u1*lo[1].y + u2*lo[2].y + u3*lo[3].y + u4*lo[4].y;
    rl.z = u0*lo[0].z + u1*lo[1].z + u2*lo[2].z + u3*lo[3].z + u4*lo[4].z;
    rl.w = u0*lo[0].w + u1*lo[1].w + u2*lo[2].w + u3*lo[3].w + u4*lo[4].w;
    rh.x = u0*hi[0].x + u1*hi[1].x + u2*hi[2].x + u3*hi[3].x + u4*hi[4].x;
    rh.y = u0*hi[0].y + u1*hi[1].y + u2*hi[2].y + u3*hi[3].y + u4*hi[4].y;
    rh.z = u0*hi[0].z + u1*hi[1].z + u2*hi[2].z + u3*hi[3].z + u4*hi[4].z;
    rh.w = u0*hi[0].w + u1*hi[1].w + u2*hi[2].w + u3*hi[3].w + u4*hi[4].w;
    *(uint4*)(kout + j) = pack8(rl, rh);
  }
}

// ---------------- fused q-GEMM + score (LDS-staged) -------------------------------
// One block per n (1024), 256 thr = 4 waves. Phase 1: q80x256 = xb_rows @ Wq^T with
// gemm_mfma-style staged LDS (As 80x64, Bs 256x64, XOR-swizzled); wave w owns cols
// [w*64, w*64+64). Epilogue -> qlds[t][s][fh] (union'd over As/Bs). Phase 2: score
// ssum[n,t,c] = sum_s sigmoid(qk/8)*prior[t,s,c] - bps[n%256,t,c]  (round-6 code).
__global__ __launch_bounds__(256) void qscore(const ushort_t* __restrict__ xb,
                                              const ushort_t* __restrict__ Wtq,
                                              const ushort_t* __restrict__ kbuf,
                                              const float* __restrict__ prior,
                                              const float* __restrict__ bps,
                                              float* __restrict__ ssum) {
  __shared__ __align__(16) char smem[46080];           // union: As+Bs (43K) | qlds (45K)
  ushort_t* As_ = (ushort_t*)smem;                     // [80*64]
  ushort_t* Bs_ = (ushort_t*)(smem + 10240);           // [256*64]
  ushort_t* qlds = (ushort_t*)smem;                    // [5*64*72]
  const int n = blockIdx.x;
  const int tid = threadIdx.x;
  const int lane = tid & 63, w = tid >> 6;
  const int cl = lane & 15, ql = lane >> 4, l7 = lane & 7;
  const ushort_t* A = xb + (size_t)n * 20480;          // 80 rows x 256

  // hoist k fragments for the score phase (overlaps with GEMM)
  const int c = w * 16 + cl;
  const int nb = n & 255;
  const ushort_t* kbp = kbuf + (size_t)(n >> 2) * 16384 + (n & 3) * 64;
  bf16x8 kfr0 = *(const bf16x8*)(kbp + c * 256 + ql * 8);
  bf16x8 kfr1 = *(const bf16x8*)(kbp + c * 256 + ql * 8 + 32);

  f32x4 acc[5][4];
#pragma unroll
  for (int mi = 0; mi < 5; ++mi)
#pragma unroll
    for (int ni = 0; ni < 4; ++ni) acc[mi][ni] = (f32x4){0.f, 0.f, 0.f, 0.f};

  for (int t4 = 0; t4 < 4; ++t4) {
    const int k0 = t4 * 64;
    if (t4) __syncthreads();
#pragma unroll
    for (int l = 0; l < 3; ++l) {              // A: 640 16B chunks
      int i = l * 256 + tid;
      if (i < 640) {
        int r = i >> 3, cc = i & 7;
        uint4 v = *(const uint4*)(A + (size_t)r * 256 + k0 + cc * 8);
        *(uint4*)&As_[r * 64 + ((cc ^ (r & 7)) * 8)] = v;
      }
    }
#pragma unroll
    for (int l = 0; l < 8; ++l) {              // B: 2048 16B chunks
      int i = l * 256 + tid;
      int nn = i >> 3, cc = i & 7;
      uint4 v = *(const uint4*)(Wtq + (size_t)nn * 256 + k0 + cc * 8);
      *(uint4*)&Bs_[nn * 64 + ((cc ^ (nn & 7)) * 8)] = v;
    }
    __syncthreads();
#pragma unroll
    for (int kk = 0; kk < 2; ++kk) {
      const int offk = (((kk << 2) | ql) ^ l7) * 8;
      bf16x8 bfr[4];
#pragma unroll
      for (int ni = 0; ni < 4; ++ni)
        bfr[ni] = *(const bf16x8*)&Bs_[(w * 64 + ni * 16 + cl) * 64 + offk];
#pragma unroll
      for (int mi = 0; mi < 5; ++mi) {
        bf16x8 afr = *(const bf16x8*)&As_[(mi * 16 + cl) * 64 + offk];
#pragma unroll
        for (int ni = 0; ni < 4; ++ni)
          acc[mi][ni] = __builtin_amdgcn_mfma_f32_16x16x32_bf16(afr, bfr[ni], acc[mi][ni], 0, 0, 0);
      }
    }
  }
  __syncthreads();                             // staging reads done; reuse smem as qlds
  // epilogue -> qlds [t=mi][s=16ql+4rr+w][fh=ni*16+cl], stride 72
#pragma unroll
  for (int mi = 0; mi < 5; ++mi)
#pragma unroll
    for (int ni = 0; ni < 4; ++ni)
#pragma unroll
      for (int rr = 0; rr < 4; ++rr)
        qlds[(mi * 64 + 16 * ql + 4 * rr + w) * 72 + ni * 16 + cl] = f2bf(acc[mi][ni][rr]);
  __syncthreads();

  // score phase: wave w owns cols c = w*16 + cl (round-6 proven code)
#pragma unroll
  for (int t = 0; t < 5; ++t) {
    f32x4 sacc[4];
#pragma unroll
    for (int si = 0; si < 4; ++si) {
      bf16x8 a0 = *(const bf16x8*)&qlds[(t * 64 + si * 16 + cl) * 72 + ql * 8];
      bf16x8 a1 = *(const bf16x8*)&qlds[(t * 64 + si * 16 + cl) * 72 + ql * 8 + 32];
      f32x4 z = (f32x4){0.f, 0.f, 0.f, 0.f};
      z = __builtin_amdgcn_mfma_f32_16x16x32_bf16(a0, kfr0, z, 0, 0, 0);
      z = __builtin_amdgcn_mfma_f32_16x16x32_bf16(a1, kfr1, z, 0, 0, 0);
      sacc[si] = z;
    }
    const float* pp = prior + t * 4096;
    float colsum = 0.f;
#pragma unroll
    for (int si = 0; si < 4; ++si) {
#pragma unroll
      for (int r = 0; r < 4; ++r) {
        int s = si * 16 + ql * 4 + r;
        float sg = 1.f / (1.f + __expf(-sacc[si][r] * 0.125f));
        colsum += sg * pp[s * 64 + c];
      }
    }
    colsum += __shfl_xor(colsum, 16);
    colsum += __shfl_xor(colsum, 32);
    if (ql == 0)
      ssum[(size_t)n * 320 + t * 64 + c] = colsum - bps[((size_t)nb * 5 + t) * 64 + c];
  }
}

// ---------------- MFMA GEMM: C_bf16[M,256] = A_bf16 @ Wt^T ------------------------
// SCALE: acc *= ssum[row*4 + col/64] (v-GEMM). SEEPI: fused SE avg/max (o-GEMM).
// NOTE: C may equal A (in-place); C not restrict.
template<int SCALE, int SEEPI>
__global__ __launch_bounds__(512, 4) void gemm_mfma(
    const ushort_t* __restrict__ A, const ushort_t* __restrict__ Wt,
    ushort_t* C, const float* __restrict__ ssum,
    float* __restrict__ ravg, float* __restrict__ rmax) {
  __shared__ __align__(16) ushort_t As_[128 * 64];
  __shared__ __align__(16) ushort_t Bs_[256 * 64];
  __shared__ float redS[8], redM[8];
  const int tid = threadIdx.x;
  const int lane = tid & 63;
  const int w = tid >> 6, wr = w >> 2, wc = w & 3;
  const int row0 = blockIdx.x * 128;
  const int cl = lane & 15, ql = lane >> 4, l7 = lane & 7;

  f32x4 acc[4][4];
#pragma unroll
  for (int i = 0; i < 4; ++i)
#pragma unroll
    for (int j = 0; j < 4; ++j) acc[i][j] = (f32x4){0.f, 0.f, 0.f, 0.f};

  for (int t = 0; t < 4; ++t) {
    const int k0 = t * 64;
    if (t) __syncthreads();
#pragma unroll
    for (int l = 0; l < 2; ++l) {              // A: 1024 16B chunks
      int i = l * 512 + tid;
      int r = i >> 3, c = i & 7;
      uint4 v = *(const uint4*)(A + (size_t)(row0 + r) * 256 + k0 + c * 8);
      *(uint4*)&As_[r * 64 + ((c ^ (r & 7)) * 8)] = v;
    }
#pragma unroll
    for (int l = 0; l < 4; ++l) {              // B: 2048 16B chunks
      int i = l * 512 + tid;
      int n = i >> 3, c = i & 7;
      uint4 v = *(const uint4*)(Wt + (size_t)n * 256 + k0 + c * 8);
      *(uint4*)&Bs_[n * 64 + ((c ^ (n & 7)) * 8)] = v;
    }
    __syncthreads();
#pragma unroll
    for (int kk = 0; kk < 2; ++kk) {
      const int offk = (((kk << 2) | ql) ^ l7) * 8;
      bf16x8 bfr[4], afr[4];
#pragma unroll
      for (int ni = 0; ni < 4; ++ni)
        bfr[ni] = *(const bf16x8*)&Bs_[(wc * 64 + ni * 16 + cl) * 64 + offk];
#pragma unroll
      for (int mi = 0; mi < 4; ++mi)
        afr[mi] = *(const bf16x8*)&As_[(wr * 64 + mi * 16 + cl) * 64 + offk];
#pragma unroll
      for (int mi = 0; mi < 4; ++mi)
#pragma unroll
        for (int ni = 0; ni < 4; ++ni)
          acc[mi][ni] = __builtin_amdgcn_mfma_f32_16x16x32_bf16(afr[mi], bfr[ni], acc[mi][ni], 0, 0, 0);
    }
  }
  // epilogue: D row = wr*64+mi*16+ql*4+r, col = wc*64+ni*16+cl
  float lsum = 0.f, lmax = -3.4e38f;
#pragma unroll
  for (int mi = 0; mi < 4; ++mi) {
    float sc[4];
    if (SCALE) {
#pragma unroll
      for (int r = 0; r < 4; ++r)
        sc[r] = ssum[(size_t)(row0 + wr * 64 + mi * 16 + ql * 4 + r) * 4 + wc];
    }
#pragma unroll
    for (int ni = 0; ni < 4; ++ni) {
      int col = wc * 64 + ni * 16 + cl;
      f32x4 v = acc[mi][ni];
#pragma unroll
      for (int r = 0; r < 4; ++r) {
        int row = row0 + wr * 64 + mi * 16 + ql * 4 + r;
        float f = v[r];
        if (SCALE) f *= sc[r];
        C[(size_t)row * 256 + col] = f2bf(f);
        if (SEEPI) { lsum += f; lmax = fmaxf(lmax, f); }
      }
    }
  }
  if (SEEPI) {
#pragma unroll
    for (int off = 32; off; off >>= 1) {
      lsum += __shfl_xor(lsum, off);
      lmax = fmaxf(lmax, __shfl_xor(lmax, off));
    }
    if (lane == 0) { redS[w] = lsum; redM[w] = lmax; }
    __syncthreads();
    if (tid < 2) {                             // group bt = row0/64 + tid
      float s = redS[tid * 4] + redS[tid * 4 + 1] + redS[tid * 4 + 2] + redS[tid * 4 + 3];
      float m = fmaxf(fmaxf(redM[tid * 4], redM[tid * 4 + 1]),
                      fmaxf(redM[tid * 4 + 2], redM[tid * 4 + 3]));
      ravg[blockIdx.x * 2 + tid] = s * (1.f / 16384.f);
      rmax[blockIdx.x * 2 + tid] = m;
    }
  }
}

// ---------------- final: out = bf16(o)*se[b,t] + bf16(x), se computed inline ------
__global__ __launch_bounds__(256) void final_kernel(
    const ushort_t* __restrict__ xb, const ushort_t* __restrict__ ob,
    const float* __restrict__ ravg, const float* __restrict__ rmax,
    const float* __restrict__ fc1w, const float* __restrict__ fc1b,
    const float* __restrict__ fc2w, const float* __restrict__ fc2b,
    const float* __restrict__ bili, float* __restrict__ out) {
  __shared__ float sse;
  int i = blockIdx.x * 256 + threadIdx.x;      // float4 id, 5242880
  size_t j = (size_t)i * 4;
  int bt = (int)(j >> 14);
  uint2 uo = *(const uint2*)(ob + j);          // issue loads before serial SE
  uint2 ux = *(const uint2*)(xb + j);
  if (threadIdx.x == 0) {
    int b = bt / 5, t = bt % 5;
    float avg[5], mx[5];
    for (int tt = 0; tt < 5; ++tt) { avg[tt] = ravg[b * 5 + tt]; mx[tt] = rmax[b * 5 + tt]; }
    float w = bili[0];
    float s12[2];
    for (int p = 0; p < 2; ++p) {
      const float* in = p == 0 ? avg : mx;
      float a = fc2b[t];
      for (int jj = 0; jj < 25; ++jj) {
        float hh = fc1b[jj];
        for (int tt = 0; tt < 5; ++tt) hh += in[tt] * fc1w[tt * 25 + jj];
        a += fmaxf(hh, 0.f) * fc2w[jj * 5 + t];
      }
      s12[p] = 1.f / (1.f + __expf(-a));
    }
    sse = (1.f - w) * s12[0] + w * s12[1];
  }
  __syncthreads();
  float s = sse;
  float4 r = {bflo(uo.x) * s + bflo(ux.x), bfhi(uo.x) * s + bfhi(ux.x),
              bflo(uo.y) * s + bflo(ux.y), bfhi(uo.y) * s + bfhi(ux.y)};
  *(float4*)(out + j) = r;
}

extern "C" void kernel_launch(void* const* d_in, const int* in_sizes, int n_in,
                              void* d_out, int out_size, void* d_ws, size_t ws_size,
                              hipStream_t stream) {
  const float* x     = (const float*)d_in[0];
  const float* bias  = (const float*)d_in[1];
  const float* Wq    = (const float*)d_in[2];
  const float* Wv    = (const float*)d_in[3];
  const float* Wo    = (const float*)d_in[4];
  const float* u_t   = (const float*)d_in[5];
  const float* dis   = (const float*)d_in[6];
  const float* sigma = (const float*)d_in[7];
  const float* fc1w  = (const float*)d_in[8];
  const float* fc1b  = (const float*)d_in[9];
  const float* fc2w  = (const float*)d_in[10];
  const float* fc2b  = (const float*)d_in[11];
  const float* bili  = (const float*)d_in[12];
  float* out = (float*)d_out;

  // workspace layout (bytes), ~94.5 MB. qvb carries v*ssum -> o (in place).
  char* wsb = (char*)d_ws;
  ushort_t* xbuf = (ushort_t*)wsb;             wsb += 41943040;  // bf16(x), alive to end
  ushort_t* qvb  = (ushort_t*)wsb;             wsb += 41943040;  // v*s / o
  ushort_t* kb   = (ushort_t*)wsb;             wsb += 8388608;   // k bf16 [B,S,F]
  ushort_t* Wt   = (ushort_t*)wsb;             wsb += 393216;    // 3 x W^T bf16
  float*    ssum = (float*)wsb;                wsb += 1310720;
  float*    prior= (float*)wsb;                wsb += 81920;
  float*    bps  = (float*)wsb;                wsb += 327680;
  float*    ravg = (float*)wsb;                wsb += 5120;
  float*    rmax = (float*)wsb;                wsb += 5120;

  // 1) fused prep: Wt | prior | bps | (k, xb)
  prep_kernel<<<4176, 256, 0, stream>>>(x, u_t, Wq, Wv, Wo, dis, sigma, bias,
                                        Wt, prior, bps, kb, xbuf);
  // 2) fused q-GEMM + score (q never touches HBM)
  qscore<<<1024, 256, 0, stream>>>(xbuf, Wt, kb, prior, bps, ssum);
  // 3) v = xb @ Wv, scaled by ssum in epilogue
  gemm_mfma<1, 0><<<640, 512, 0, stream>>>(xbuf, Wt + 65536, qvb, ssum, nullptr, nullptr);
  // 4) o = (v.*s) @ Wo -> qvb IN PLACE, fused SE avg/max
  gemm_mfma<0, 1><<<640, 512, 0, stream>>>(qvb, Wt + 131072, qvb, nullptr, ravg, rmax);
  // 5) final with inline SE MLP
  final_kernel<<<20480, 256, 0, stream>>>(xbuf, qvb, ravg, rmax,
                                          fc1w, fc1b, fc2w, fc2b, bili, out);
}